// Round 2
// baseline (352.128 us; speedup 1.0000x reference)
//
#include <hip/hip_runtime.h>
#include <hip/hip_bf16.h>
#include <math.h>

#define SEQ 2048
#define DM 2048
#define NH 16
#define HD 128
#define QKV_N 6144

typedef __bf16 bf16;
typedef __bf16 bf16x8 __attribute__((ext_vector_type(8)));
typedef __bf16 bf16x4v __attribute__((ext_vector_type(4)));
typedef __bf16 bf16x2v __attribute__((ext_vector_type(2)));
typedef float f32x4 __attribute__((ext_vector_type(4)));

// 64-elem-row swizzle (8 chunk slots, 128B row = full bank revolution)
__device__ inline int sw_idx64(int row, int chunk) {
    return (row * 8 + (chunk ^ (row & 7))) * 8;
}
// 128-elem-row swizzle (16 chunk slots, 256B row)
__device__ inline int sw_idx128(int row, int chunk) {
    return (row * 16 + (chunk ^ (row & 15))) * 8;
}

__device__ inline void async16(const void* g, void* l) {
    __builtin_amdgcn_global_load_lds((const __attribute__((address_space(1))) void*)g,
                                     (__attribute__((address_space(3))) void*)l, 16, 0, 0);
}

// ---- weight transposes (z<4) + x fp32->bf16 convert (z==4) ----------------
__global__ void k_prep(const float* __restrict__ wq, const float* __restrict__ wk,
                       const float* __restrict__ wv, const float* __restrict__ wo,
                       bf16* __restrict__ wT, bf16* __restrict__ woT,
                       const float* __restrict__ x, bf16* __restrict__ xb) {
    const int z = blockIdx.z;
    int tx = threadIdx.x, ty = threadIdx.y;
    if (z == 4) {                                    // x convert: 1M float4s
        int bid = blockIdx.y * 64 + blockIdx.x;
        if (bid >= 1024) return;
        int i = bid * 1024 + ty * 32 + tx;
        float4 v = ((const float4*)x)[i];
        bf16x4v o;
        o.x = (bf16)v.x; o.y = (bf16)v.y; o.z = (bf16)v.z; o.w = (bf16)v.w;
        ((bf16x4v*)xb)[i] = o;
        return;
    }
    __shared__ float tile[32][33];
    const float* src = (z == 0) ? wq : (z == 1) ? wk : (z == 2) ? wv : wo;
    bf16* dst = (z < 3) ? (wT + (size_t)z * DM * DM) : woT;
    int bx = blockIdx.x * 32, by = blockIdx.y * 32;
    tile[ty][tx] = src[(size_t)(by + ty) * DM + bx + tx];
    __syncthreads();
    dst[(size_t)(bx + ty) * DM + by + tx] = (bf16)tile[tx][ty];
}

// ---- V transpose only (RoPE is fused into the QKV GEMM epilogue) ----------
__global__ void k_post(const bf16* __restrict__ qkv, bf16* __restrict__ vT) {
    __shared__ bf16 tile[32][33];
    int tx = threadIdx.x, ty = threadIdx.y;
    int bx = blockIdx.x * 32, by = blockIdx.y * 32;  // bx: channel, by: seq
    tile[ty][tx] = qkv[(size_t)(by + ty) * QKV_N + 2 * DM + bx + tx];
    __syncthreads();
    vT[(size_t)(bx + ty) * SEQ + by + tx] = tile[tx][ty];
}

// ---- C[M][N] = A[M][K] * Bt[N][K]^T, 128 x BN tile, BK=64 -----------------
// ROPE: apply rotary to cols < 4096 (Q|K) on the fp32 accumulator before the
// bf16 store. Pair (2i,2i+1) lives in adjacent lanes -> one shfl_xor(.,1).
template <typename OutT, int BN, bool ROPE>
__global__ __launch_bounds__(256) void k_gemm_bt(const bf16* __restrict__ A,
                                                 const bf16* __restrict__ Bt,
                                                 OutT* __restrict__ C,
                                                 const float* __restrict__ cosT,
                                                 const float* __restrict__ sinT,
                                                 int M, int N, int K) {
    constexpr int NI = BN / 32;
    __shared__ bf16 As[128 * 64];
    __shared__ bf16 Bs[BN * 64];
    const int t = threadIdx.x;
    const int lane = t & 63;
    const int w = t >> 6;
    const int wr = (w >> 1) * 64, wc = (w & 1) * (BN / 2);
    const int l15 = lane & 15, quad = lane >> 4;
    const size_t bm = (size_t)blockIdx.y * 128, bn = (size_t)blockIdx.x * BN;
    f32x4 acc[4][NI];
#pragma unroll
    for (int i = 0; i < 4; ++i)
#pragma unroll
        for (int j = 0; j < NI; ++j) acc[i][j] = (f32x4){0.f, 0.f, 0.f, 0.f};

    for (int kt = 0; kt < K; kt += 64) {
#pragma unroll
        for (int j = 0; j < 4; ++j) {
            int c = j * 256 + t;
            int row = c >> 3, g = ((c & 7) ^ (row & 7)) * 8;
            async16(&A[(bm + row) * K + kt + g], &As[c * 8]);
        }
#pragma unroll
        for (int j = 0; j < NI; ++j) {
            int c = j * 256 + t;
            int row = c >> 3, g = ((c & 7) ^ (row & 7)) * 8;
            async16(&Bt[(bn + row) * K + kt + g], &Bs[c * 8]);
        }
        __syncthreads();
#pragma unroll
        for (int kh = 0; kh < 2; ++kh) {
            bf16x8 af[4], bfm[NI];
#pragma unroll
            for (int mi = 0; mi < 4; ++mi)
                af[mi] = *(const bf16x8*)&As[sw_idx64(wr + mi * 16 + l15, kh * 4 + quad)];
#pragma unroll
            for (int ni = 0; ni < NI; ++ni)
                bfm[ni] = *(const bf16x8*)&Bs[sw_idx64(wc + ni * 16 + l15, kh * 4 + quad)];
#pragma unroll
            for (int mi = 0; mi < 4; ++mi)
#pragma unroll
                for (int ni = 0; ni < NI; ++ni)
                    acc[mi][ni] = __builtin_amdgcn_mfma_f32_16x16x32_bf16(
                        af[mi], bfm[ni], acc[mi][ni], 0, 0, 0);
        }
        __syncthreads();
    }
    const bool doRope = ROPE && (bn < 4096);         // uniform per block (BN|4096)
#pragma unroll
    for (int mi = 0; mi < 4; ++mi)
#pragma unroll
        for (int ni = 0; ni < NI; ++ni)
#pragma unroll
            for (int r = 0; r < 4; ++r) {
                size_t row = bm + wr + mi * 16 + quad * 4 + r;
                size_t col = bn + wc + ni * 16 + l15;
                float v = acc[mi][ni][r];
                if (ROPE) {
                    float p = __shfl_xor(v, 1);      // partner of the rot pair
                    if (doRope) {
                        int i = ((int)col & 127) >> 1;
                        float cc = cosT[(int)row * 64 + i];
                        float ss = sinT[(int)row * 64 + i];
                        // even col: re*c - im*s ; odd col: re*s + im*c
                        v = v * cc + ss * ((lane & 1) ? p : -p);
                    }
                }
                C[row * (size_t)N + col] = (OutT)v;
            }
}

// ---- causal flash attention, HD=128, 64-key tiles, LDS double-buffer ------
// 256 threads = 4 waves; block owns 64 q-rows. Tile t+1 staged (8 async16 per
// thread) BEFORE computing tile t; s_waitcnt vmcnt(8) retires exactly tile-t's
// loads (issued one full tile earlier -> HBM latency hidden).  LDS: 2x16KB K +
// 2x16KB V + 8KB P = 72KB -> 2 blocks/CU.  n64 = qb+1 tiles: causal-exact,
// only the last tile is masked. Unnormalized no-max softmax (shift-invariant).
__global__ __launch_bounds__(256) void k_flash(const bf16* __restrict__ qkv,
                                               const bf16* __restrict__ vT,
                                               bf16* __restrict__ out) {
    __shared__ bf16 Ks[2][64 * 128];                 // [key][d] swizzled
    __shared__ bf16 Vs[2][128 * 64];                 // [ch][key] swizzled
    __shared__ bf16 Pl[4][16 * 64];                  // per-wave, swizzled
    const int t = threadIdx.x;
    const int lane = t & 63;
    const int w = t >> 6;
    const int l15 = lane & 15, quad = lane >> 4;
    const int b = blockIdx.x;
    const int h = (b & 7) * 2 + ((b >> 3) & 1);      // 2 heads per XCD slot
    const int qb = 31 - (b >> 4);                    // heavy first
    const int q0w = qb * 64 + w * 16;
    const float sc = 0.08838834764831845f;           // 1/sqrt(128)

    const size_t qrow = (size_t)(q0w + l15) * QKV_N + h * HD;
    bf16x8 aq[4];
#pragma unroll
    for (int u = 0; u < 4; ++u)
        aq[u] = *(const bf16x8*)&qkv[qrow + u * 32 + quad * 8];

    f32x4 o[8];
#pragma unroll
    for (int c = 0; c < 8; ++c) o[c] = (f32x4){0.f, 0.f, 0.f, 0.f};
    float l_r[4] = {0.f, 0.f, 0.f, 0.f};

    // staging descriptors: 1024 chunks per matrix per tile, 4/thread each
    int krow[4], kg[4], vrow[4], vg[4];
#pragma unroll
    for (int j = 0; j < 4; ++j) {
        int c = j * 256 + t;
        krow[j] = c >> 4; kg[j] = ((c & 15) ^ (krow[j] & 15)) * 8;   // 16 chunks/row
        vrow[j] = c >> 3; vg[j] = ((c & 7) ^ (vrow[j] & 7)) * 8;     //  8 chunks/row
    }
    auto stage = [&](int buf, int kt2) {
        const int kb2 = kt2 * 64;
#pragma unroll
        for (int j = 0; j < 4; ++j)
            async16(&qkv[(size_t)(kb2 + krow[j]) * QKV_N + DM + h * HD + kg[j]],
                    &Ks[buf][(j * 256 + t) * 8]);
#pragma unroll
        for (int j = 0; j < 4; ++j)
            async16(&vT[(size_t)(h * HD + vrow[j]) * SEQ + kb2 + vg[j]],
                    &Vs[buf][(j * 256 + t) * 8]);
    };

    const int n64 = qb + 1;                          // exact causal tile count
    stage(0, 0);
    for (int kt = 0; kt < n64; ++kt) {
        const int cb = kt & 1;
        const int kbase = kt * 64;
        if (kt + 1 < n64) {
            stage(cb ^ 1, kt + 1);                   // prefetch next tile
            asm volatile("s_waitcnt vmcnt(8)" ::: "memory");   // tile-t loads done
        } else {
            asm volatile("s_waitcnt vmcnt(0)" ::: "memory");
        }
        __builtin_amdgcn_s_barrier();
        asm volatile("" ::: "memory");

        // ---- QK^T: 4 key sub-tiles x 4 d-chunks ----
        f32x4 s4[4];
#pragma unroll
        for (int sub = 0; sub < 4; ++sub) {
            f32x4 z = (f32x4){0.f, 0.f, 0.f, 0.f};
#pragma unroll
            for (int u = 0; u < 4; ++u) {
                bf16x8 kv = *(const bf16x8*)&Ks[cb][sw_idx128(sub * 16 + l15, u * 4 + quad)];
                z = __builtin_amdgcn_mfma_f32_16x16x32_bf16(aq[u], kv, z, 0, 0, 0);
            }
            s4[sub] = z;
        }
        const bool masked = (kt == n64 - 1);
#pragma unroll
        for (int sub = 0; sub < 4; ++sub)
#pragma unroll
            for (int r = 0; r < 4; ++r) {
                float p = __expf(s4[sub][r] * sc);
                if (masked)
                    p = (kbase + sub * 16 + l15 <= q0w + quad * 4 + r) ? p : 0.f;
                l_r[r] += p;
                int rowp = quad * 4 + r;
                int col = sub * 16 + l15;
                Pl[w][(rowp * 8 + ((col >> 3) ^ (rowp & 7))) * 8 + (col & 7)] = (bf16)p;
            }
        __asm__ __volatile__("s_waitcnt lgkmcnt(0)" ::: "memory");
        bf16x8 pf[2];
#pragma unroll
        for (int kk = 0; kk < 2; ++kk)
            pf[kk] = *(const bf16x8*)&Pl[w][sw_idx64(l15, kk * 4 + quad)];
        __builtin_amdgcn_s_setprio(1);
#pragma unroll
        for (int c = 0; c < 8; ++c)
#pragma unroll
            for (int kk = 0; kk < 2; ++kk) {
                bf16x8 vb = *(const bf16x8*)&Vs[cb][sw_idx64(c * 16 + l15, kk * 4 + quad)];
                o[c] = __builtin_amdgcn_mfma_f32_16x16x32_bf16(pf[kk], vb, o[c], 0, 0, 0);
            }
        __builtin_amdgcn_s_setprio(0);
        asm volatile("" ::: "memory");
        __builtin_amdgcn_s_barrier();                // all waves done reading buf cb
        asm volatile("" ::: "memory");
    }

    float rl[4];
#pragma unroll
    for (int r = 0; r < 4; ++r) {
        float l = l_r[r];
        l += __shfl_xor(l, 1, 16);
        l += __shfl_xor(l, 2, 16);
        l += __shfl_xor(l, 4, 16);
        l += __shfl_xor(l, 8, 16);
        rl[r] = 1.0f / l;
    }
#pragma unroll
    for (int c = 0; c < 8; ++c)
#pragma unroll
        for (int r = 0; r < 4; ++r)
            out[(size_t)(q0w + quad * 4 + r) * DM + h * HD + c * 16 + l15] =
                (bf16)(o[c][r] * rl[r]);
}

extern "C" void kernel_launch(void* const* d_in, const int* in_sizes, int n_in,
                              void* d_out, int out_size, void* d_ws, size_t ws_size,
                              hipStream_t stream) {
    const float* x  = (const float*)d_in[0];
    const float* fc = (const float*)d_in[1];
    const float* fs = (const float*)d_in[2];
    // d_in[3] = mask (unused; causal mask applied analytically)
    const float* wq = (const float*)d_in[4];
    const float* wk = (const float*)d_in[5];
    const float* wv = (const float*)d_in[6];
    const float* wo = (const float*)d_in[7];
    float* out = (float*)d_out;

    char* ws = (char*)d_ws;
    bf16* xb  = (bf16*)(ws);                          //  8MB, reused as attn_out
    bf16* wT  = (bf16*)(ws + (size_t)(8u  << 20));    // 24MB  (wq|wk|wv transposed)
    bf16* woT = (bf16*)(ws + (size_t)(32u << 20));    //  8MB
    bf16* qkv = (bf16*)(ws + (size_t)(40u << 20));    // 24MB  [seq][6144]
    bf16* vT  = (bf16*)(ws + (size_t)(64u << 20));    //  8MB  [c][seq]

    k_prep<<<dim3(64, 64, 5), dim3(32, 32), 0, stream>>>(wq, wk, wv, wo, wT, woT, x, xb);
    k_gemm_bt<bf16, 128, true><<<dim3(48, 16), 256, 0, stream>>>(xb, wT, qkv, fc, fs,
                                                                 SEQ, QKV_N, DM);
    k_post<<<dim3(64, 64), dim3(32, 32), 0, stream>>>(qkv, vT);
    k_flash<<<512, 256, 0, stream>>>(qkv, vT, xb);
    k_gemm_bt<float, 64, false><<<dim3(32, 16), 256, 0, stream>>>(xb, woT, out,
                                                                  nullptr, nullptr,
                                                                  SEQ, DM, DM);
}

// Round 3
// 308.644 us; speedup vs baseline: 1.1409x; 1.1409x over previous
//
#include <hip/hip_runtime.h>
#include <hip/hip_bf16.h>
#include <math.h>

#define SEQ 2048
#define DM 2048
#define NH 16
#define HD 128
#define QK_N 4096

typedef __bf16 bf16;
typedef __bf16 bf16x8 __attribute__((ext_vector_type(8)));
typedef __bf16 bf16x4v __attribute__((ext_vector_type(4)));
typedef __bf16 bf16x2v __attribute__((ext_vector_type(2)));
typedef float f32x4 __attribute__((ext_vector_type(4)));

// 64-elem-row swizzle (8 chunk slots, 128B row = full bank revolution)
__device__ inline int sw_idx64(int row, int chunk) {
    return (row * 8 + (chunk ^ (row & 7))) * 8;
}
// 128-elem-row swizzle (16 chunk slots, 256B row)
__device__ inline int sw_idx128(int row, int chunk) {
    return (row * 16 + (chunk ^ (row & 15))) * 8;
}

__device__ inline void async16(const void* g, void* l) {
    __builtin_amdgcn_global_load_lds((const __attribute__((address_space(1))) void*)g,
                                     (__attribute__((address_space(3))) void*)l, 16, 0, 0);
}

// ---- weight transposes (z<4, 64x64 tiles, float4 loads) + x convert (z=4) --
__global__ __launch_bounds__(256) void k_prep(const float* __restrict__ wq,
                                              const float* __restrict__ wk,
                                              const float* __restrict__ wv,
                                              const float* __restrict__ wo,
                                              bf16* __restrict__ wT, bf16* __restrict__ woT,
                                              const float* __restrict__ x,
                                              bf16* __restrict__ xb) {
    const int z = blockIdx.z;
    const int t = threadIdx.x;
    if (z == 4) {                                    // x convert: 1M float4s
        int bid = blockIdx.y * 32 + blockIdx.x;      // 0..1023
#pragma unroll
        for (int j = 0; j < 4; ++j) {
            int i = bid * 1024 + j * 256 + t;
            float4 v = ((const float4*)x)[i];
            bf16x4v o;
            o.x = (bf16)v.x; o.y = (bf16)v.y; o.z = (bf16)v.z; o.w = (bf16)v.w;
            ((bf16x4v*)xb)[i] = o;
        }
        return;
    }
    __shared__ bf16 tile[64][68];                    // 68: 8B-aligned rows, low conflict
    const float* src = (z == 0) ? wq : (z == 1) ? wk : (z == 2) ? wv : wo;
    bf16* dst = (z < 3) ? (wT + (size_t)z * DM * DM) : woT;
    const int bx = blockIdx.x * 64, by = blockIdx.y * 64;
#pragma unroll
    for (int j = 0; j < 4; ++j) {
        int idx = j * 256 + t;                       // 0..1023
        int r = idx >> 4, cg = idx & 15;
        float4 v = *(const float4*)&src[(size_t)(by + r) * DM + bx + cg * 4];
        bf16x4v o;
        o.x = (bf16)v.x; o.y = (bf16)v.y; o.z = (bf16)v.z; o.w = (bf16)v.w;
        *(bf16x4v*)&tile[r][cg * 4] = o;
    }
    __syncthreads();
#pragma unroll
    for (int j = 0; j < 4; ++j) {
        int idx = j * 256 + t;
        int r = idx >> 4, cg = idx & 15;
        bf16x4v o;
        o.x = tile[cg * 4 + 0][r];
        o.y = tile[cg * 4 + 1][r];
        o.z = tile[cg * 4 + 2][r];
        o.w = tile[cg * 4 + 3][r];
        *(bf16x4v*)&dst[(size_t)(bx + r) * DM + by + cg * 4] = o;
    }
}

// ---- coalesced RoPE on Q,K in-place (qk layout [seq][4096]) ---------------
__global__ __launch_bounds__(1024) void k_rope(bf16* __restrict__ qk,
                                               const float* __restrict__ cosT,
                                               const float* __restrict__ sinT) {
    int idx = blockIdx.x * 1024 + threadIdx.x;       // 2M rot-pairs
    int i = idx & 63;
    int h = (idx >> 6) & 15;
    int s = idx >> 10;
    float c = cosT[s * 64 + i], sn = sinT[s * 64 + i];
    size_t base = (size_t)s * QK_N + h * HD + 2 * i;
    bf16x2v q = *(bf16x2v*)&qk[base];
    float qr = (float)q.x, qi = (float)q.y;
    bf16x2v qo;
    qo.x = (bf16)(qr * c - qi * sn);
    qo.y = (bf16)(qr * sn + qi * c);
    *(bf16x2v*)&qk[base] = qo;
    bf16x2v k = *(bf16x2v*)&qk[base + DM];
    float kr = (float)k.x, ki = (float)k.y;
    bf16x2v ko;
    ko.x = (bf16)(kr * c - ki * sn);
    ko.y = (bf16)(kr * sn + ki * c);
    *(bf16x2v*)&qk[base + DM] = ko;
}

// ---- shared 128xBN GEMM body: C[.][N] += A[M][K] * Bt[N][K]^T -------------
template <typename OutT, int BN>
__device__ __forceinline__ void gemm_body(const bf16* __restrict__ A,
                                          const bf16* __restrict__ Bt,
                                          OutT* __restrict__ C,
                                          int N, int K, size_t bm, size_t bn,
                                          bf16* As, bf16* Bs) {
    constexpr int NI = BN / 32;
    const int t = threadIdx.x;
    const int lane = t & 63;
    const int w = t >> 6;
    const int wr = (w >> 1) * 64, wc = (w & 1) * (BN / 2);
    const int l15 = lane & 15, quad = lane >> 4;
    f32x4 acc[4][NI];
#pragma unroll
    for (int i = 0; i < 4; ++i)
#pragma unroll
        for (int j = 0; j < NI; ++j) acc[i][j] = (f32x4){0.f, 0.f, 0.f, 0.f};

    for (int kt = 0; kt < K; kt += 64) {
#pragma unroll
        for (int j = 0; j < 4; ++j) {
            int c = j * 256 + t;
            int row = c >> 3, g = ((c & 7) ^ (row & 7)) * 8;
            async16(&A[(bm + row) * K + kt + g], &As[c * 8]);
        }
#pragma unroll
        for (int j = 0; j < NI; ++j) {
            int c = j * 256 + t;
            int row = c >> 3, g = ((c & 7) ^ (row & 7)) * 8;
            async16(&Bt[(bn + row) * K + kt + g], &Bs[c * 8]);
        }
        __syncthreads();
#pragma unroll
        for (int kh = 0; kh < 2; ++kh) {
            bf16x8 af[4], bfm[NI];
#pragma unroll
            for (int mi = 0; mi < 4; ++mi)
                af[mi] = *(const bf16x8*)&As[sw_idx64(wr + mi * 16 + l15, kh * 4 + quad)];
#pragma unroll
            for (int ni = 0; ni < NI; ++ni)
                bfm[ni] = *(const bf16x8*)&Bs[sw_idx64(wc + ni * 16 + l15, kh * 4 + quad)];
#pragma unroll
            for (int mi = 0; mi < 4; ++mi)
#pragma unroll
                for (int ni = 0; ni < NI; ++ni)
                    acc[mi][ni] = __builtin_amdgcn_mfma_f32_16x16x32_bf16(
                        af[mi], bfm[ni], acc[mi][ni], 0, 0, 0);
        }
        __syncthreads();
    }
#pragma unroll
    for (int mi = 0; mi < 4; ++mi)
#pragma unroll
        for (int ni = 0; ni < NI; ++ni)
#pragma unroll
            for (int r = 0; r < 4; ++r) {
                size_t row = bm + wr + mi * 16 + quad * 4 + r;
                size_t col = bn + wc + ni * 16 + l15;
                C[row * (size_t)N + col] = (OutT)acc[mi][ni][r];
            }
}

// ---- combined QK-gemm (blocks 0..511) + V^T-gemm (blocks 512..767) --------
// QK: C=qk[s][4096] = xb[2048][2048] * wT(q|k)[4096][2048]^T
// V:  C=vT[c][2048] = wvT[2048][2048] * xb[2048][2048]^T   (V transposed for free)
__global__ __launch_bounds__(256) void k_gemm_qkv(const bf16* __restrict__ xb,
                                                  const bf16* __restrict__ wT,
                                                  bf16* __restrict__ qk,
                                                  bf16* __restrict__ vT) {
    __shared__ bf16 As[128 * 64];
    __shared__ bf16 Bs[128 * 64];
    const int b = blockIdx.x;
    if (b < 512) {
        size_t bm = (size_t)(b >> 5) * 128, bn = (size_t)(b & 31) * 128;
        gemm_body<bf16, 128>(xb, wT, qk, QK_N, DM, bm, bn, As, Bs);
    } else {
        int b2 = b - 512;
        size_t bm = (size_t)(b2 >> 4) * 128, bn = (size_t)(b2 & 15) * 128;
        gemm_body<bf16, 128>(wT + (size_t)2 * DM * DM, xb, vT, SEQ, DM, bm, bn, As, Bs);
    }
}

// ---- final projection GEMM: out = attn * woT^T (fp32 out) -----------------
template <typename OutT, int BN>
__global__ __launch_bounds__(256) void k_gemm_bt(const bf16* __restrict__ A,
                                                 const bf16* __restrict__ Bt,
                                                 OutT* __restrict__ C,
                                                 int M, int N, int K) {
    __shared__ bf16 As[128 * 64];
    __shared__ bf16 Bs[BN * 64];
    size_t bm = (size_t)blockIdx.y * 128, bn = (size_t)blockIdx.x * BN;
    gemm_body<OutT, BN>(A, Bt, C, N, K, bm, bn, As, Bs);
}

// ---- causal flash attention, HD=128, 64-key tiles, LDS double-buffer ------
// 256 threads = 4 waves; block owns 64 q-rows. Tile t+1 staged (8 async16 per
// thread) BEFORE computing tile t; s_waitcnt vmcnt(8) retires exactly tile-t's
// loads (issued one full tile earlier). LDS 72KB -> 2 blocks/CU.
__global__ __launch_bounds__(256) void k_flash(const bf16* __restrict__ qk,
                                               const bf16* __restrict__ vT,
                                               bf16* __restrict__ out) {
    __shared__ bf16 Ks[2][64 * 128];                 // [key][d] swizzled
    __shared__ bf16 Vs[2][128 * 64];                 // [ch][key] swizzled
    __shared__ bf16 Pl[4][16 * 64];                  // per-wave, swizzled
    const int t = threadIdx.x;
    const int lane = t & 63;
    const int w = t >> 6;
    const int l15 = lane & 15, quad = lane >> 4;
    const int b = blockIdx.x;
    const int h = (b & 7) * 2 + ((b >> 3) & 1);      // 2 heads per XCD slot
    const int qb = 31 - (b >> 4);                    // heavy first
    const int q0w = qb * 64 + w * 16;
    const float sc2 = 0.08838834764831845f * 1.4426950408889634f;  // /sqrt(128)*log2e

    const size_t qrow = (size_t)(q0w + l15) * QK_N + h * HD;
    bf16x8 aq[4];
#pragma unroll
    for (int u = 0; u < 4; ++u)
        aq[u] = *(const bf16x8*)&qk[qrow + u * 32 + quad * 8];

    f32x4 o[8];
#pragma unroll
    for (int c = 0; c < 8; ++c) o[c] = (f32x4){0.f, 0.f, 0.f, 0.f};
    float l_r[4] = {0.f, 0.f, 0.f, 0.f};

    // staging descriptors: 1024 chunks per matrix per tile, 4/thread each
    int krow[4], kg[4], vrow[4], vg[4];
#pragma unroll
    for (int j = 0; j < 4; ++j) {
        int c = j * 256 + t;
        krow[j] = c >> 4; kg[j] = ((c & 15) ^ (krow[j] & 15)) * 8;   // 16 chunks/row
        vrow[j] = c >> 3; vg[j] = ((c & 7) ^ (vrow[j] & 7)) * 8;     //  8 chunks/row
    }
    auto stage = [&](int buf, int kt2) {
        const int kb2 = kt2 * 64;
#pragma unroll
        for (int j = 0; j < 4; ++j)
            async16(&qk[(size_t)(kb2 + krow[j]) * QK_N + DM + h * HD + kg[j]],
                    &Ks[buf][(j * 256 + t) * 8]);
#pragma unroll
        for (int j = 0; j < 4; ++j)
            async16(&vT[(size_t)(h * HD + vrow[j]) * SEQ + kb2 + vg[j]],
                    &Vs[buf][(j * 256 + t) * 8]);
    };

    const int n64 = qb + 1;                          // exact causal tile count
    stage(0, 0);
    for (int kt = 0; kt < n64; ++kt) {
        const int cb = kt & 1;
        const int kbase = kt * 64;
        if (kt + 1 < n64) {
            stage(cb ^ 1, kt + 1);                   // prefetch next tile
            asm volatile("s_waitcnt vmcnt(8)" ::: "memory");   // tile-t loads done
        } else {
            asm volatile("s_waitcnt vmcnt(0)" ::: "memory");
        }
        __builtin_amdgcn_s_barrier();
        asm volatile("" ::: "memory");

        // ---- QK^T: 4 key sub-tiles x 4 d-chunks ----
        f32x4 s4[4];
#pragma unroll
        for (int sub = 0; sub < 4; ++sub) {
            f32x4 z = (f32x4){0.f, 0.f, 0.f, 0.f};
#pragma unroll
            for (int u = 0; u < 4; ++u) {
                bf16x8 kv = *(const bf16x8*)&Ks[cb][sw_idx128(sub * 16 + l15, u * 4 + quad)];
                z = __builtin_amdgcn_mfma_f32_16x16x32_bf16(aq[u], kv, z, 0, 0, 0);
            }
            s4[sub] = z;
        }
        const bool masked = (kt == n64 - 1);
#pragma unroll
        for (int sub = 0; sub < 4; ++sub)
#pragma unroll
            for (int r = 0; r < 4; ++r) {
                float p = exp2f(s4[sub][r] * sc2);
                if (masked)
                    p = (kbase + sub * 16 + l15 <= q0w + quad * 4 + r) ? p : 0.f;
                l_r[r] += p;
                int rowp = quad * 4 + r;
                int col = sub * 16 + l15;
                Pl[w][(rowp * 8 + ((col >> 3) ^ (rowp & 7))) * 8 + (col & 7)] = (bf16)p;
            }
        __asm__ __volatile__("s_waitcnt lgkmcnt(0)" ::: "memory");
        bf16x8 pf[2];
#pragma unroll
        for (int kk = 0; kk < 2; ++kk)
            pf[kk] = *(const bf16x8*)&Pl[w][sw_idx64(l15, kk * 4 + quad)];
        __builtin_amdgcn_s_setprio(1);
#pragma unroll
        for (int c = 0; c < 8; ++c)
#pragma unroll
            for (int kk = 0; kk < 2; ++kk) {
                bf16x8 vb = *(const bf16x8*)&Vs[cb][sw_idx64(c * 16 + l15, kk * 4 + quad)];
                o[c] = __builtin_amdgcn_mfma_f32_16x16x32_bf16(pf[kk], vb, o[c], 0, 0, 0);
            }
        __builtin_amdgcn_s_setprio(0);
        asm volatile("" ::: "memory");
        __builtin_amdgcn_s_barrier();                // all waves done reading buf cb
        asm volatile("" ::: "memory");
    }

    float rl[4];
#pragma unroll
    for (int r = 0; r < 4; ++r) {
        float l = l_r[r];
        l += __shfl_xor(l, 1, 16);
        l += __shfl_xor(l, 2, 16);
        l += __shfl_xor(l, 4, 16);
        l += __shfl_xor(l, 8, 16);
        rl[r] = 1.0f / l;
    }
#pragma unroll
    for (int c = 0; c < 8; ++c)
#pragma unroll
        for (int r = 0; r < 4; ++r)
            out[(size_t)(q0w + quad * 4 + r) * DM + h * HD + c * 16 + l15] =
                (bf16)(o[c][r] * rl[r]);
}

extern "C" void kernel_launch(void* const* d_in, const int* in_sizes, int n_in,
                              void* d_out, int out_size, void* d_ws, size_t ws_size,
                              hipStream_t stream) {
    const float* x  = (const float*)d_in[0];
    const float* fc = (const float*)d_in[1];
    const float* fs = (const float*)d_in[2];
    // d_in[3] = mask (unused; causal mask applied analytically)
    const float* wq = (const float*)d_in[4];
    const float* wk = (const float*)d_in[5];
    const float* wv = (const float*)d_in[6];
    const float* wo = (const float*)d_in[7];
    float* out = (float*)d_out;

    char* ws = (char*)d_ws;
    bf16* xb  = (bf16*)(ws);                          //  8MB, reused as attn_out
    bf16* wT  = (bf16*)(ws + (size_t)(8u  << 20));    // 24MB  (wq^T|wk^T|wv^T)
    bf16* woT = (bf16*)(ws + (size_t)(32u << 20));    //  8MB
    bf16* qk  = (bf16*)(ws + (size_t)(40u << 20));    // 16MB  [seq][4096]
    bf16* vT  = (bf16*)(ws + (size_t)(64u << 20));    //  8MB  [c][seq]

    k_prep<<<dim3(32, 32, 5), 256, 0, stream>>>(wq, wk, wv, wo, wT, woT, x, xb);
    k_gemm_qkv<<<768, 256, 0, stream>>>(xb, wT, qk, vT);
    k_rope<<<2048, 1024, 0, stream>>>(qk, fc, fs);
    k_flash<<<512, 256, 0, stream>>>(qk, vT, xb);
    k_gemm_bt<float, 64><<<dim3(32, 16), 256, 0, stream>>>(xb, woT, out, SEQ, DM, DM);
}

// Round 4
// 304.895 us; speedup vs baseline: 1.1549x; 1.0123x over previous
//
#include <hip/hip_runtime.h>
#include <hip/hip_bf16.h>
#include <math.h>

#define SEQ 2048
#define DM 2048
#define NH 16
#define HD 128
#define QKV_N 6144

typedef __bf16 bf16;
typedef __bf16 bf16x8 __attribute__((ext_vector_type(8)));
typedef __bf16 bf16x4v __attribute__((ext_vector_type(4)));
typedef __bf16 bf16x2v __attribute__((ext_vector_type(2)));
typedef float f32x4 __attribute__((ext_vector_type(4)));

// 64-elem-row swizzle (8 chunk slots, 128B row = full bank revolution)
__device__ inline int sw_idx64(int row, int chunk) {
    return (row * 8 + (chunk ^ (row & 7))) * 8;
}
// 128-elem-row swizzle (16 chunk slots, 256B row)
__device__ inline int sw_idx128(int row, int chunk) {
    return (row * 16 + (chunk ^ (row & 15))) * 8;
}

__device__ inline void async16(const void* g, void* l) {
    __builtin_amdgcn_global_load_lds((const __attribute__((address_space(1))) void*)g,
                                     (__attribute__((address_space(3))) void*)l, 16, 0, 0);
}

// ---- weight transposes (z<4, 64x64 tiles, float4 loads) + x convert (z=4) --
__global__ __launch_bounds__(256) void k_prep(const float* __restrict__ wq,
                                              const float* __restrict__ wk,
                                              const float* __restrict__ wv,
                                              const float* __restrict__ wo,
                                              bf16* __restrict__ wT, bf16* __restrict__ woT,
                                              const float* __restrict__ x,
                                              bf16* __restrict__ xb) {
    const int z = blockIdx.z;
    const int t = threadIdx.x;
    if (z == 4) {                                    // x convert: 1M float4s
        int bid = blockIdx.y * 32 + blockIdx.x;      // 0..1023
#pragma unroll
        for (int j = 0; j < 4; ++j) {
            int i = bid * 1024 + j * 256 + t;
            float4 v = ((const float4*)x)[i];
            bf16x4v o;
            o.x = (bf16)v.x; o.y = (bf16)v.y; o.z = (bf16)v.z; o.w = (bf16)v.w;
            ((bf16x4v*)xb)[i] = o;
        }
        return;
    }
    __shared__ bf16 tile[64][66];
    const float* src = (z == 0) ? wq : (z == 1) ? wk : (z == 2) ? wv : wo;
    bf16* dst = (z < 3) ? (wT + (size_t)z * DM * DM) : woT;
    const int bx = blockIdx.x * 64, by = blockIdx.y * 64;
#pragma unroll
    for (int j = 0; j < 4; ++j) {
        int idx = j * 256 + t;                       // 0..1023
        int r = idx >> 4, cg = idx & 15;
        float4 v = *(const float4*)&src[(size_t)(by + r) * DM + bx + cg * 4];
        bf16x4v o;
        o.x = (bf16)v.x; o.y = (bf16)v.y; o.z = (bf16)v.z; o.w = (bf16)v.w;
        *(bf16x4v*)&tile[r][cg * 4] = o;
    }
    __syncthreads();
#pragma unroll
    for (int j = 0; j < 4; ++j) {
        int idx = j * 256 + t;
        int r = idx >> 4, cg = idx & 15;
        bf16x4v o;
        o.x = tile[cg * 4 + 0][r];
        o.y = tile[cg * 4 + 1][r];
        o.z = tile[cg * 4 + 2][r];
        o.w = tile[cg * 4 + 3][r];
        *(bf16x4v*)&dst[(size_t)(bx + r) * DM + by + cg * 4] = o;
    }
}

// ---- coalesced RoPE on Q,K in-place (qkv layout [seq][6144]) --------------
__global__ __launch_bounds__(1024) void k_rope(bf16* __restrict__ qkv,
                                               const float* __restrict__ cosT,
                                               const float* __restrict__ sinT) {
    int idx = blockIdx.x * 1024 + threadIdx.x;       // 2M rot-pairs
    int i = idx & 63;
    int h = (idx >> 6) & 15;
    int s = idx >> 10;
    float c = cosT[s * 64 + i], sn = sinT[s * 64 + i];
    size_t base = (size_t)s * QKV_N + h * HD + 2 * i;
    bf16x2v q = *(bf16x2v*)&qkv[base];
    float qr = (float)q.x, qi = (float)q.y;
    bf16x2v qo;
    qo.x = (bf16)(qr * c - qi * sn);
    qo.y = (bf16)(qr * sn + qi * c);
    *(bf16x2v*)&qkv[base] = qo;
    bf16x2v k = *(bf16x2v*)&qkv[base + DM];
    float kr = (float)k.x, ki = (float)k.y;
    bf16x2v ko;
    ko.x = (bf16)(kr * c - ki * sn);
    ko.y = (bf16)(kr * sn + ki * c);
    *(bf16x2v*)&qkv[base + DM] = ko;
}

// ---- V transpose: vT[c][s] = qkv[s][2*DM + c], 64x64 tiles ----------------
__global__ __launch_bounds__(256) void k_vt(const bf16* __restrict__ qkv,
                                            bf16* __restrict__ vT) {
    __shared__ bf16 tile[64][66];
    const int t = threadIdx.x;
    const int bx = blockIdx.x * 64, by = blockIdx.y * 64;  // bx: channel, by: seq
#pragma unroll
    for (int j = 0; j < 4; ++j) {
        int idx = j * 256 + t;
        int r = idx >> 4, cg = idx & 15;             // r: seq-row, cg: channel/4
        *(bf16x4v*)&tile[r][cg * 4] =
            *(const bf16x4v*)&qkv[(size_t)(by + r) * QKV_N + 2 * DM + bx + cg * 4];
    }
    __syncthreads();
#pragma unroll
    for (int j = 0; j < 4; ++j) {
        int idx = j * 256 + t;
        int r = idx >> 4, cg = idx & 15;             // r: channel-row, cg: seq/4
        bf16x4v o;
        o.x = tile[cg * 4 + 0][r];
        o.y = tile[cg * 4 + 1][r];
        o.z = tile[cg * 4 + 2][r];
        o.w = tile[cg * 4 + 3][r];
        *(bf16x4v*)&vT[(size_t)(bx + r) * SEQ + by + cg * 4] = o;
    }
}

// ---- shared 128xBN GEMM body: C[.][N] = A[M][K] * Bt[N][K]^T --------------
template <typename OutT, int BN>
__device__ __forceinline__ void gemm_body(const bf16* __restrict__ A,
                                          const bf16* __restrict__ Bt,
                                          OutT* __restrict__ C,
                                          int N, int K, size_t bm, size_t bn,
                                          bf16* As, bf16* Bs) {
    constexpr int NI = BN / 32;
    const int t = threadIdx.x;
    const int lane = t & 63;
    const int w = t >> 6;
    const int wr = (w >> 1) * 64, wc = (w & 1) * (BN / 2);
    const int l15 = lane & 15, quad = lane >> 4;
    f32x4 acc[4][NI];
#pragma unroll
    for (int i = 0; i < 4; ++i)
#pragma unroll
        for (int j = 0; j < NI; ++j) acc[i][j] = (f32x4){0.f, 0.f, 0.f, 0.f};

    for (int kt = 0; kt < K; kt += 64) {
#pragma unroll
        for (int j = 0; j < 4; ++j) {
            int c = j * 256 + t;
            int row = c >> 3, g = ((c & 7) ^ (row & 7)) * 8;
            async16(&A[(bm + row) * K + kt + g], &As[c * 8]);
        }
#pragma unroll
        for (int j = 0; j < NI; ++j) {
            int c = j * 256 + t;
            int row = c >> 3, g = ((c & 7) ^ (row & 7)) * 8;
            async16(&Bt[(bn + row) * K + kt + g], &Bs[c * 8]);
        }
        __syncthreads();
#pragma unroll
        for (int kh = 0; kh < 2; ++kh) {
            bf16x8 af[4], bfm[NI];
#pragma unroll
            for (int mi = 0; mi < 4; ++mi)
                af[mi] = *(const bf16x8*)&As[sw_idx64(wr + mi * 16 + l15, kh * 4 + quad)];
#pragma unroll
            for (int ni = 0; ni < NI; ++ni)
                bfm[ni] = *(const bf16x8*)&Bs[sw_idx64(wc + ni * 16 + l15, kh * 4 + quad)];
#pragma unroll
            for (int mi = 0; mi < 4; ++mi)
#pragma unroll
                for (int ni = 0; ni < NI; ++ni)
                    acc[mi][ni] = __builtin_amdgcn_mfma_f32_16x16x32_bf16(
                        af[mi], bfm[ni], acc[mi][ni], 0, 0, 0);
        }
        __syncthreads();
    }
#pragma unroll
    for (int mi = 0; mi < 4; ++mi)
#pragma unroll
        for (int ni = 0; ni < NI; ++ni)
#pragma unroll
            for (int r = 0; r < 4; ++r) {
                size_t row = bm + wr + mi * 16 + quad * 4 + r;
                size_t col = bn + wc + ni * 16 + l15;
                C[row * (size_t)N + col] = (OutT)acc[mi][ni][r];
            }
}

template <typename OutT, int BN>
__global__ __launch_bounds__(256) void k_gemm_bt(const bf16* __restrict__ A,
                                                 const bf16* __restrict__ Bt,
                                                 OutT* __restrict__ C,
                                                 int M, int N, int K) {
    __shared__ bf16 As[128 * 64];
    __shared__ bf16 Bs[BN * 64];
    size_t bm = (size_t)blockIdx.y * 128, bn = (size_t)blockIdx.x * BN;
    gemm_body<OutT, BN>(A, Bt, C, N, K, bm, bn, As, Bs);
}

// ---- causal flash attention, HD=128, 64-key tiles, LDS double-buffer ------
// 256 threads = 4 waves; block owns 64 q-rows. Tile t+1 staged (8 async16 per
// thread) BEFORE computing tile t; s_waitcnt vmcnt(8) retires exactly tile-t's
// loads (issued one full tile earlier). LDS 72KB -> 2 blocks/CU.
__global__ __launch_bounds__(256) void k_flash(const bf16* __restrict__ qkv,
                                               const bf16* __restrict__ vT,
                                               bf16* __restrict__ out) {
    __shared__ bf16 Ks[2][64 * 128];                 // [key][d] swizzled
    __shared__ bf16 Vs[2][128 * 64];                 // [ch][key] swizzled
    __shared__ bf16 Pl[4][16 * 64];                  // per-wave, swizzled
    const int t = threadIdx.x;
    const int lane = t & 63;
    const int w = t >> 6;
    const int l15 = lane & 15, quad = lane >> 4;
    const int b = blockIdx.x;
    const int h = (b & 7) * 2 + ((b >> 3) & 1);      // 2 heads per XCD slot
    const int qb = 31 - (b >> 4);                    // heavy first
    const int q0w = qb * 64 + w * 16;
    const float sc2 = 0.08838834764831845f * 1.4426950408889634f;  // /sqrt(128)*log2e

    const size_t qrow = (size_t)(q0w + l15) * QKV_N + h * HD;
    bf16x8 aq[4];
#pragma unroll
    for (int u = 0; u < 4; ++u)
        aq[u] = *(const bf16x8*)&qkv[qrow + u * 32 + quad * 8];

    f32x4 o[8];
#pragma unroll
    for (int c = 0; c < 8; ++c) o[c] = (f32x4){0.f, 0.f, 0.f, 0.f};
    float l_r[4] = {0.f, 0.f, 0.f, 0.f};

    // staging descriptors: 1024 chunks per matrix per tile, 4/thread each
    int krow[4], kg[4], vrow[4], vg[4];
#pragma unroll
    for (int j = 0; j < 4; ++j) {
        int c = j * 256 + t;
        krow[j] = c >> 4; kg[j] = ((c & 15) ^ (krow[j] & 15)) * 8;   // 16 chunks/row
        vrow[j] = c >> 3; vg[j] = ((c & 7) ^ (vrow[j] & 7)) * 8;     //  8 chunks/row
    }
    auto stage = [&](int buf, int kt2) {
        const int kb2 = kt2 * 64;
#pragma unroll
        for (int j = 0; j < 4; ++j)
            async16(&qkv[(size_t)(kb2 + krow[j]) * QKV_N + DM + h * HD + kg[j]],
                    &Ks[buf][(j * 256 + t) * 8]);
#pragma unroll
        for (int j = 0; j < 4; ++j)
            async16(&vT[(size_t)(h * HD + vrow[j]) * SEQ + kb2 + vg[j]],
                    &Vs[buf][(j * 256 + t) * 8]);
    };

    const int n64 = qb + 1;                          // exact causal tile count
    stage(0, 0);
    for (int kt = 0; kt < n64; ++kt) {
        const int cb = kt & 1;
        const int kbase = kt * 64;
        if (kt + 1 < n64) {
            stage(cb ^ 1, kt + 1);                   // prefetch next tile
            asm volatile("s_waitcnt vmcnt(8)" ::: "memory");   // tile-t loads done
        } else {
            asm volatile("s_waitcnt vmcnt(0)" ::: "memory");
        }
        __builtin_amdgcn_s_barrier();
        asm volatile("" ::: "memory");

        // ---- QK^T: 4 key sub-tiles x 4 d-chunks ----
        f32x4 s4[4];
#pragma unroll
        for (int sub = 0; sub < 4; ++sub) {
            f32x4 z = (f32x4){0.f, 0.f, 0.f, 0.f};
#pragma unroll
            for (int u = 0; u < 4; ++u) {
                bf16x8 kv = *(const bf16x8*)&Ks[cb][sw_idx128(sub * 16 + l15, u * 4 + quad)];
                z = __builtin_amdgcn_mfma_f32_16x16x32_bf16(aq[u], kv, z, 0, 0, 0);
            }
            s4[sub] = z;
        }
        const bool masked = (kt == n64 - 1);
#pragma unroll
        for (int sub = 0; sub < 4; ++sub)
#pragma unroll
            for (int r = 0; r < 4; ++r) {
                float p = exp2f(s4[sub][r] * sc2);
                if (masked)
                    p = (kbase + sub * 16 + l15 <= q0w + quad * 4 + r) ? p : 0.f;
                l_r[r] += p;
                int rowp = quad * 4 + r;
                int col = sub * 16 + l15;
                Pl[w][(rowp * 8 + ((col >> 3) ^ (rowp & 7))) * 8 + (col & 7)] = (bf16)p;
            }
        __asm__ __volatile__("s_waitcnt lgkmcnt(0)" ::: "memory");
        bf16x8 pf[2];
#pragma unroll
        for (int kk = 0; kk < 2; ++kk)
            pf[kk] = *(const bf16x8*)&Pl[w][sw_idx64(l15, kk * 4 + quad)];
        __builtin_amdgcn_s_setprio(1);
#pragma unroll
        for (int c = 0; c < 8; ++c)
#pragma unroll
            for (int kk = 0; kk < 2; ++kk) {
                bf16x8 vb = *(const bf16x8*)&Vs[cb][sw_idx64(c * 16 + l15, kk * 4 + quad)];
                o[c] = __builtin_amdgcn_mfma_f32_16x16x32_bf16(pf[kk], vb, o[c], 0, 0, 0);
            }
        __builtin_amdgcn_s_setprio(0);
        asm volatile("" ::: "memory");
        __builtin_amdgcn_s_barrier();                // all waves done reading buf cb
        asm volatile("" ::: "memory");
    }

    float rl[4];
#pragma unroll
    for (int r = 0; r < 4; ++r) {
        float l = l_r[r];
        l += __shfl_xor(l, 1, 16);
        l += __shfl_xor(l, 2, 16);
        l += __shfl_xor(l, 4, 16);
        l += __shfl_xor(l, 8, 16);
        rl[r] = 1.0f / l;
    }
#pragma unroll
    for (int c = 0; c < 8; ++c)
#pragma unroll
        for (int r = 0; r < 4; ++r)
            out[(size_t)(q0w + quad * 4 + r) * DM + h * HD + c * 16 + l15] =
                (bf16)(o[c][r] * rl[r]);
}

extern "C" void kernel_launch(void* const* d_in, const int* in_sizes, int n_in,
                              void* d_out, int out_size, void* d_ws, size_t ws_size,
                              hipStream_t stream) {
    const float* x  = (const float*)d_in[0];
    const float* fc = (const float*)d_in[1];
    const float* fs = (const float*)d_in[2];
    // d_in[3] = mask (unused; causal mask applied analytically)
    const float* wq = (const float*)d_in[4];
    const float* wk = (const float*)d_in[5];
    const float* wv = (const float*)d_in[6];
    const float* wo = (const float*)d_in[7];
    float* out = (float*)d_out;

    char* ws = (char*)d_ws;
    bf16* xb  = (bf16*)(ws);                          //  8MB, reused as attn_out
    bf16* wT  = (bf16*)(ws + (size_t)(8u  << 20));    // 24MB  (wq^T|wk^T|wv^T)
    bf16* woT = (bf16*)(ws + (size_t)(32u << 20));    //  8MB
    bf16* qkv = (bf16*)(ws + (size_t)(40u << 20));    // 24MB  [seq][6144]
    bf16* vT  = (bf16*)(ws + (size_t)(64u << 20));    //  8MB  [c][seq]

    k_prep<<<dim3(32, 32, 5), 256, 0, stream>>>(wq, wk, wv, wo, wT, woT, x, xb);
    k_gemm_bt<bf16, 128><<<dim3(48, 16), 256, 0, stream>>>(xb, wT, qkv, SEQ, QKV_N, DM);
    k_rope<<<2048, 1024, 0, stream>>>(qkv, fc, fs);
    k_vt<<<dim3(32, 32), 256, 0, stream>>>(qkv, vT);
    k_flash<<<512, 256, 0, stream>>>(qkv, vT, xb);
    k_gemm_bt<float, 128><<<dim3(16, 16), 256, 0, stream>>>(xb, woT, out, SEQ, DM, DM);
}

// Round 5
// 293.016 us; speedup vs baseline: 1.2017x; 1.0405x over previous
//
#include <hip/hip_runtime.h>
#include <hip/hip_bf16.h>
#include <math.h>

#define SEQ 2048
#define DM 2048
#define NH 16
#define HD 128
#define QKV_N 6144

typedef __bf16 bf16;
typedef __bf16 bf16x8 __attribute__((ext_vector_type(8)));
typedef __bf16 bf16x4v __attribute__((ext_vector_type(4)));
typedef __bf16 bf16x2v __attribute__((ext_vector_type(2)));
typedef float f32x4 __attribute__((ext_vector_type(4)));

// 64-elem-row swizzle (8 chunk slots, 128B row = full bank revolution)
__device__ inline int sw_idx64(int row, int chunk) {
    return (row * 8 + (chunk ^ (row & 7))) * 8;
}
// 128-elem-row swizzle (16 chunk slots, 256B row)
__device__ inline int sw_idx128(int row, int chunk) {
    return (row * 16 + (chunk ^ (row & 15))) * 8;
}

__device__ inline void async16(const void* g, void* l) {
    __builtin_amdgcn_global_load_lds((const __attribute__((address_space(1))) void*)g,
                                     (__attribute__((address_space(3))) void*)l, 16, 0, 0);
}

// ---- weight transposes (z<4, 64x64 tiles, float4 loads) + x convert (z=4) --
__global__ __launch_bounds__(256) void k_prep(const float* __restrict__ wq,
                                              const float* __restrict__ wk,
                                              const float* __restrict__ wv,
                                              const float* __restrict__ wo,
                                              bf16* __restrict__ wT, bf16* __restrict__ woT,
                                              const float* __restrict__ x,
                                              bf16* __restrict__ xb) {
    const int z = blockIdx.z;
    const int t = threadIdx.x;
    if (z == 4) {                                    // x convert: 1M float4s
        int bid = blockIdx.y * 32 + blockIdx.x;      // 0..1023
#pragma unroll
        for (int j = 0; j < 4; ++j) {
            int i = bid * 1024 + j * 256 + t;
            float4 v = ((const float4*)x)[i];
            bf16x4v o;
            o.x = (bf16)v.x; o.y = (bf16)v.y; o.z = (bf16)v.z; o.w = (bf16)v.w;
            ((bf16x4v*)xb)[i] = o;
        }
        return;
    }
    __shared__ bf16 tile[64][66];
    const float* src = (z == 0) ? wq : (z == 1) ? wk : (z == 2) ? wv : wo;
    bf16* dst = (z < 3) ? (wT + (size_t)z * DM * DM) : woT;
    const int bx = blockIdx.x * 64, by = blockIdx.y * 64;
#pragma unroll
    for (int j = 0; j < 4; ++j) {
        int idx = j * 256 + t;                       // 0..1023
        int r = idx >> 4, cg = idx & 15;
        float4 v = *(const float4*)&src[(size_t)(by + r) * DM + bx + cg * 4];
        bf16x4v o;
        o.x = (bf16)v.x; o.y = (bf16)v.y; o.z = (bf16)v.z; o.w = (bf16)v.w;
        *(bf16x4v*)&tile[r][cg * 4] = o;
    }
    __syncthreads();
#pragma unroll
    for (int j = 0; j < 4; ++j) {
        int idx = j * 256 + t;
        int r = idx >> 4, cg = idx & 15;
        bf16x4v o;
        o.x = tile[cg * 4 + 0][r];
        o.y = tile[cg * 4 + 1][r];
        o.z = tile[cg * 4 + 2][r];
        o.w = tile[cg * 4 + 3][r];
        *(bf16x4v*)&dst[(size_t)(bx + r) * DM + by + cg * 4] = o;
    }
}

// ---- fused: V transpose (blocks 0..1023) + K-only RoPE (blocks 1024..3071) -
// Q RoPE is applied in-register inside k_flash (Q is read exactly once there).
__global__ __launch_bounds__(256) void k_rope_vt(bf16* __restrict__ qkv,
                                                 const float* __restrict__ cosT,
                                                 const float* __restrict__ sinT,
                                                 bf16* __restrict__ vT) {
    const int t = threadIdx.x;
    if (blockIdx.x >= 1024) {
        // K RoPE: 512K groups of 8 channels (4 rot-pairs), bf16x8 vectorized
        int g = (blockIdx.x - 1024) * 256 + t;       // 0..524287
        int s = g >> 8;                              // 256 groups per row
        int cg = g & 255;
        int h = cg >> 4, w8 = cg & 15;
        size_t base = (size_t)s * QKV_N + DM + h * HD + w8 * 8;
        float4 cv = *(const float4*)&cosT[s * 64 + w8 * 4];
        float4 sv = *(const float4*)&sinT[s * 64 + w8 * 4];
        float cc[4] = {cv.x, cv.y, cv.z, cv.w};
        float ss[4] = {sv.x, sv.y, sv.z, sv.w};
        bf16x8 k = *(bf16x8*)&qkv[base];
        bf16x8 o;
#pragma unroll
        for (int p = 0; p < 4; ++p) {
            float re = (float)k[2 * p], im = (float)k[2 * p + 1];
            o[2 * p]     = (bf16)(re * cc[p] - im * ss[p]);
            o[2 * p + 1] = (bf16)(re * ss[p] + im * cc[p]);
        }
        *(bf16x8*)&qkv[base] = o;
        return;
    }
    // V transpose: vT[c][s] = qkv[s][2*DM + c], 64x64 tiles
    __shared__ bf16 tile[64][66];
    const int bx = (blockIdx.x & 31) * 64, by = (blockIdx.x >> 5) * 64;
#pragma unroll
    for (int j = 0; j < 4; ++j) {
        int idx = j * 256 + t;
        int r = idx >> 4, cg = idx & 15;             // r: seq-row, cg: channel/4
        *(bf16x4v*)&tile[r][cg * 4] =
            *(const bf16x4v*)&qkv[(size_t)(by + r) * QKV_N + 2 * DM + bx + cg * 4];
    }
    __syncthreads();
#pragma unroll
    for (int j = 0; j < 4; ++j) {
        int idx = j * 256 + t;
        int r = idx >> 4, cg = idx & 15;             // r: channel-row, cg: seq/4
        bf16x4v o;
        o.x = tile[cg * 4 + 0][r];
        o.y = tile[cg * 4 + 1][r];
        o.z = tile[cg * 4 + 2][r];
        o.w = tile[cg * 4 + 3][r];
        *(bf16x4v*)&vT[(size_t)(bx + r) * SEQ + by + cg * 4] = o;
    }
}

// ---- shared 128xBN GEMM body: C[.][N] = A[M][K] * Bt[N][K]^T --------------
template <typename OutT, int BN>
__device__ __forceinline__ void gemm_body(const bf16* __restrict__ A,
                                          const bf16* __restrict__ Bt,
                                          OutT* __restrict__ C,
                                          int N, int K, size_t bm, size_t bn,
                                          bf16* As, bf16* Bs) {
    constexpr int NI = BN / 32;
    const int t = threadIdx.x;
    const int lane = t & 63;
    const int w = t >> 6;
    const int wr = (w >> 1) * 64, wc = (w & 1) * (BN / 2);
    const int l15 = lane & 15, quad = lane >> 4;
    f32x4 acc[4][NI];
#pragma unroll
    for (int i = 0; i < 4; ++i)
#pragma unroll
        for (int j = 0; j < NI; ++j) acc[i][j] = (f32x4){0.f, 0.f, 0.f, 0.f};

    for (int kt = 0; kt < K; kt += 64) {
#pragma unroll
        for (int j = 0; j < 4; ++j) {
            int c = j * 256 + t;
            int row = c >> 3, g = ((c & 7) ^ (row & 7)) * 8;
            async16(&A[(bm + row) * K + kt + g], &As[c * 8]);
        }
#pragma unroll
        for (int j = 0; j < NI; ++j) {
            int c = j * 256 + t;
            int row = c >> 3, g = ((c & 7) ^ (row & 7)) * 8;
            async16(&Bt[(bn + row) * K + kt + g], &Bs[c * 8]);
        }
        __syncthreads();
#pragma unroll
        for (int kh = 0; kh < 2; ++kh) {
            bf16x8 af[4], bfm[NI];
#pragma unroll
            for (int mi = 0; mi < 4; ++mi)
                af[mi] = *(const bf16x8*)&As[sw_idx64(wr + mi * 16 + l15, kh * 4 + quad)];
#pragma unroll
            for (int ni = 0; ni < NI; ++ni)
                bfm[ni] = *(const bf16x8*)&Bs[sw_idx64(wc + ni * 16 + l15, kh * 4 + quad)];
#pragma unroll
            for (int mi = 0; mi < 4; ++mi)
#pragma unroll
                for (int ni = 0; ni < NI; ++ni)
                    acc[mi][ni] = __builtin_amdgcn_mfma_f32_16x16x32_bf16(
                        af[mi], bfm[ni], acc[mi][ni], 0, 0, 0);
        }
        __syncthreads();
    }
#pragma unroll
    for (int mi = 0; mi < 4; ++mi)
#pragma unroll
        for (int ni = 0; ni < NI; ++ni)
#pragma unroll
            for (int r = 0; r < 4; ++r) {
                size_t row = bm + wr + mi * 16 + quad * 4 + r;
                size_t col = bn + wc + ni * 16 + l15;
                C[row * (size_t)N + col] = (OutT)acc[mi][ni][r];
            }
}

template <typename OutT, int BN>
__global__ __launch_bounds__(256) void k_gemm_bt(const bf16* __restrict__ A,
                                                 const bf16* __restrict__ Bt,
                                                 OutT* __restrict__ C,
                                                 int M, int N, int K) {
    __shared__ bf16 As[128 * 64];
    __shared__ bf16 Bs[BN * 64];
    size_t bm = (size_t)blockIdx.y * 128, bn = (size_t)blockIdx.x * BN;
    gemm_body<OutT, BN>(A, Bt, C, N, K, bm, bn, As, Bs);
}

// ---- causal flash attention, HD=128, 64-key tiles, LDS double-buffer ------
// 256 threads = 4 waves; block owns 64 q-rows. Tile t+1 staged (8 async16 per
// thread) BEFORE computing tile t; s_waitcnt vmcnt(8) retires exactly tile-t's
// loads (issued one full tile earlier). LDS 72KB -> 2 blocks/CU.
// Q RoPE applied in-register on the aq fragments (Q in qkv is un-roped).
__global__ __launch_bounds__(256) void k_flash(const bf16* __restrict__ qkv,
                                               const bf16* __restrict__ vT,
                                               const float* __restrict__ cosT,
                                               const float* __restrict__ sinT,
                                               bf16* __restrict__ out) {
    __shared__ bf16 Ks[2][64 * 128];                 // [key][d] swizzled
    __shared__ bf16 Vs[2][128 * 64];                 // [ch][key] swizzled
    __shared__ bf16 Pl[4][16 * 64];                  // per-wave, swizzled
    const int t = threadIdx.x;
    const int lane = t & 63;
    const int w = t >> 6;
    const int l15 = lane & 15, quad = lane >> 4;
    const int b = blockIdx.x;
    const int h = (b & 7) * 2 + ((b >> 3) & 1);      // 2 heads per XCD slot
    const int qb = 31 - (b >> 4);                    // heavy first
    const int q0w = qb * 64 + w * 16;
    const float sc2 = 0.08838834764831845f * 1.4426950408889634f;  // /sqrt(128)*log2e

    const size_t qrow = (size_t)(q0w + l15) * QKV_N + h * HD;
    bf16x8 aq[4];
#pragma unroll
    for (int u = 0; u < 4; ++u)
        aq[u] = *(const bf16x8*)&qkv[qrow + u * 32 + quad * 8];
    // in-register Q RoPE: lane's 8 consecutive channels = 4 complete rot-pairs;
    // pair index i = u*16 + quad*4 + p, tables at cosT[(q0w+l15)*64 + i].
#pragma unroll
    for (int u = 0; u < 4; ++u) {
        float4 cv = *(const float4*)&cosT[(q0w + l15) * 64 + u * 16 + quad * 4];
        float4 sv = *(const float4*)&sinT[(q0w + l15) * 64 + u * 16 + quad * 4];
        float cc[4] = {cv.x, cv.y, cv.z, cv.w};
        float ss[4] = {sv.x, sv.y, sv.z, sv.w};
        bf16x8 q = aq[u], rq;
#pragma unroll
        for (int p = 0; p < 4; ++p) {
            float re = (float)q[2 * p], im = (float)q[2 * p + 1];
            rq[2 * p]     = (bf16)(re * cc[p] - im * ss[p]);
            rq[2 * p + 1] = (bf16)(re * ss[p] + im * cc[p]);
        }
        aq[u] = rq;
    }

    f32x4 o[8];
#pragma unroll
    for (int c = 0; c < 8; ++c) o[c] = (f32x4){0.f, 0.f, 0.f, 0.f};
    float l_r[4] = {0.f, 0.f, 0.f, 0.f};

    // staging descriptors: 1024 chunks per matrix per tile, 4/thread each
    int krow[4], kg[4], vrow[4], vg[4];
#pragma unroll
    for (int j = 0; j < 4; ++j) {
        int c = j * 256 + t;
        krow[j] = c >> 4; kg[j] = ((c & 15) ^ (krow[j] & 15)) * 8;   // 16 chunks/row
        vrow[j] = c >> 3; vg[j] = ((c & 7) ^ (vrow[j] & 7)) * 8;     //  8 chunks/row
    }
    auto stage = [&](int buf, int kt2) {
        const int kb2 = kt2 * 64;
#pragma unroll
        for (int j = 0; j < 4; ++j)
            async16(&qkv[(size_t)(kb2 + krow[j]) * QKV_N + DM + h * HD + kg[j]],
                    &Ks[buf][(j * 256 + t) * 8]);
#pragma unroll
        for (int j = 0; j < 4; ++j)
            async16(&vT[(size_t)(h * HD + vrow[j]) * SEQ + kb2 + vg[j]],
                    &Vs[buf][(j * 256 + t) * 8]);
    };

    const int n64 = qb + 1;                          // exact causal tile count
    stage(0, 0);
    for (int kt = 0; kt < n64; ++kt) {
        const int cb = kt & 1;
        const int kbase = kt * 64;
        if (kt + 1 < n64) {
            stage(cb ^ 1, kt + 1);                   // prefetch next tile
            asm volatile("s_waitcnt vmcnt(8)" ::: "memory");   // tile-t loads done
        } else {
            asm volatile("s_waitcnt vmcnt(0)" ::: "memory");
        }
        __builtin_amdgcn_s_barrier();
        asm volatile("" ::: "memory");

        // ---- QK^T: 4 key sub-tiles x 4 d-chunks ----
        f32x4 s4[4];
#pragma unroll
        for (int sub = 0; sub < 4; ++sub) {
            f32x4 z = (f32x4){0.f, 0.f, 0.f, 0.f};
#pragma unroll
            for (int u = 0; u < 4; ++u) {
                bf16x8 kv = *(const bf16x8*)&Ks[cb][sw_idx128(sub * 16 + l15, u * 4 + quad)];
                z = __builtin_amdgcn_mfma_f32_16x16x32_bf16(aq[u], kv, z, 0, 0, 0);
            }
            s4[sub] = z;
        }
        const bool masked = (kt == n64 - 1);
#pragma unroll
        for (int sub = 0; sub < 4; ++sub)
#pragma unroll
            for (int r = 0; r < 4; ++r) {
                float p = exp2f(s4[sub][r] * sc2);
                if (masked)
                    p = (kbase + sub * 16 + l15 <= q0w + quad * 4 + r) ? p : 0.f;
                l_r[r] += p;
                int rowp = quad * 4 + r;
                int col = sub * 16 + l15;
                Pl[w][(rowp * 8 + ((col >> 3) ^ (rowp & 7))) * 8 + (col & 7)] = (bf16)p;
            }
        __asm__ __volatile__("s_waitcnt lgkmcnt(0)" ::: "memory");
        bf16x8 pf[2];
#pragma unroll
        for (int kk = 0; kk < 2; ++kk)
            pf[kk] = *(const bf16x8*)&Pl[w][sw_idx64(l15, kk * 4 + quad)];
        __builtin_amdgcn_s_setprio(1);
#pragma unroll
        for (int c = 0; c < 8; ++c)
#pragma unroll
            for (int kk = 0; kk < 2; ++kk) {
                bf16x8 vb = *(const bf16x8*)&Vs[cb][sw_idx64(c * 16 + l15, kk * 4 + quad)];
                o[c] = __builtin_amdgcn_mfma_f32_16x16x32_bf16(pf[kk], vb, o[c], 0, 0, 0);
            }
        __builtin_amdgcn_s_setprio(0);
        asm volatile("" ::: "memory");
        __builtin_amdgcn_s_barrier();                // all waves done reading buf cb
        asm volatile("" ::: "memory");
    }

    float rl[4];
#pragma unroll
    for (int r = 0; r < 4; ++r) {
        float l = l_r[r];
        l += __shfl_xor(l, 1, 16);
        l += __shfl_xor(l, 2, 16);
        l += __shfl_xor(l, 4, 16);
        l += __shfl_xor(l, 8, 16);
        rl[r] = 1.0f / l;
    }
#pragma unroll
    for (int c = 0; c < 8; ++c)
#pragma unroll
        for (int r = 0; r < 4; ++r)
            out[(size_t)(q0w + quad * 4 + r) * DM + h * HD + c * 16 + l15] =
                (bf16)(o[c][r] * rl[r]);
}

extern "C" void kernel_launch(void* const* d_in, const int* in_sizes, int n_in,
                              void* d_out, int out_size, void* d_ws, size_t ws_size,
                              hipStream_t stream) {
    const float* x  = (const float*)d_in[0];
    const float* fc = (const float*)d_in[1];
    const float* fs = (const float*)d_in[2];
    // d_in[3] = mask (unused; causal mask applied analytically)
    const float* wq = (const float*)d_in[4];
    const float* wk = (const float*)d_in[5];
    const float* wv = (const float*)d_in[6];
    const float* wo = (const float*)d_in[7];
    float* out = (float*)d_out;

    char* ws = (char*)d_ws;
    bf16* xb  = (bf16*)(ws);                          //  8MB, reused as attn_out
    bf16* wT  = (bf16*)(ws + (size_t)(8u  << 20));    // 24MB  (wq^T|wk^T|wv^T)
    bf16* woT = (bf16*)(ws + (size_t)(32u << 20));    //  8MB
    bf16* qkv = (bf16*)(ws + (size_t)(40u << 20));    // 24MB  [seq][6144]
    bf16* vT  = (bf16*)(ws + (size_t)(64u << 20));    //  8MB  [c][seq]

    k_prep<<<dim3(32, 32, 5), 256, 0, stream>>>(wq, wk, wv, wo, wT, woT, x, xb);
    k_gemm_bt<bf16, 128><<<dim3(48, 16), 256, 0, stream>>>(xb, wT, qkv, SEQ, QKV_N, DM);
    k_rope_vt<<<3072, 256, 0, stream>>>(qkv, fc, fs, vT);
    k_flash<<<512, 256, 0, stream>>>(qkv, vT, fc, fs, xb);
    k_gemm_bt<float, 64><<<dim3(32, 16), 256, 0, stream>>>(xb, woT, out, SEQ, DM, DM);
}

// Round 6
// 285.473 us; speedup vs baseline: 1.2335x; 1.0264x over previous
//
#include <hip/hip_runtime.h>
#include <hip/hip_bf16.h>
#include <math.h>

#define SEQ 2048
#define DM 2048
#define NH 16
#define HD 128
#define QKV_N 6144

typedef __bf16 bf16;
typedef __bf16 bf16x8 __attribute__((ext_vector_type(8)));
typedef __bf16 bf16x4v __attribute__((ext_vector_type(4)));
typedef __bf16 bf16x2v __attribute__((ext_vector_type(2)));
typedef float f32x4 __attribute__((ext_vector_type(4)));

// 64-elem-row swizzle (8 chunk slots, 128B row = full bank revolution)
__device__ inline int sw_idx64(int row, int chunk) {
    return (row * 8 + (chunk ^ (row & 7))) * 8;
}
// 128-elem-row swizzle (16 chunk slots, 256B row)
__device__ inline int sw_idx128(int row, int chunk) {
    return (row * 16 + (chunk ^ (row & 15))) * 8;
}

__device__ inline void async16(const void* g, void* l) {
    __builtin_amdgcn_global_load_lds((const __attribute__((address_space(1))) void*)g,
                                     (__attribute__((address_space(3))) void*)l, 16, 0, 0);
}

// ---- weight transposes (z<4, 64x64 tiles, float4 loads) + x convert (z=4) --
__global__ __launch_bounds__(256) void k_prep(const float* __restrict__ wq,
                                              const float* __restrict__ wk,
                                              const float* __restrict__ wv,
                                              const float* __restrict__ wo,
                                              bf16* __restrict__ wT, bf16* __restrict__ woT,
                                              const float* __restrict__ x,
                                              bf16* __restrict__ xb) {
    const int z = blockIdx.z;
    const int t = threadIdx.x;
    if (z == 4) {                                    // x convert: 1M float4s
        int bid = blockIdx.y * 32 + blockIdx.x;      // 0..1023
#pragma unroll
        for (int j = 0; j < 4; ++j) {
            int i = bid * 1024 + j * 256 + t;
            float4 v = ((const float4*)x)[i];
            bf16x4v o;
            o.x = (bf16)v.x; o.y = (bf16)v.y; o.z = (bf16)v.z; o.w = (bf16)v.w;
            ((bf16x4v*)xb)[i] = o;
        }
        return;
    }
    __shared__ bf16 tile[64][66];
    const float* src = (z == 0) ? wq : (z == 1) ? wk : (z == 2) ? wv : wo;
    bf16* dst = (z < 3) ? (wT + (size_t)z * DM * DM) : woT;
    const int bx = blockIdx.x * 64, by = blockIdx.y * 64;
#pragma unroll
    for (int j = 0; j < 4; ++j) {
        int idx = j * 256 + t;                       // 0..1023
        int r = idx >> 4, cg = idx & 15;
        float4 v = *(const float4*)&src[(size_t)(by + r) * DM + bx + cg * 4];
        bf16x4v o;
        o.x = (bf16)v.x; o.y = (bf16)v.y; o.z = (bf16)v.z; o.w = (bf16)v.w;
        *(bf16x4v*)&tile[r][cg * 4] = o;
    }
    __syncthreads();
#pragma unroll
    for (int j = 0; j < 4; ++j) {
        int idx = j * 256 + t;
        int r = idx >> 4, cg = idx & 15;
        bf16x4v o;
        o.x = tile[cg * 4 + 0][r];
        o.y = tile[cg * 4 + 1][r];
        o.z = tile[cg * 4 + 2][r];
        o.w = tile[cg * 4 + 3][r];
        *(bf16x4v*)&dst[(size_t)(bx + r) * DM + by + cg * 4] = o;
    }
}

// ---- fused: V transpose (blocks 0..1023) + K-only RoPE (blocks 1024..3071) -
// Q RoPE is applied in-register inside k_flash (Q is read exactly once there).
__global__ __launch_bounds__(256) void k_rope_vt(bf16* __restrict__ qkv,
                                                 const float* __restrict__ cosT,
                                                 const float* __restrict__ sinT,
                                                 bf16* __restrict__ vT) {
    const int t = threadIdx.x;
    if (blockIdx.x >= 1024) {
        // K RoPE: 512K groups of 8 channels (4 rot-pairs), bf16x8 vectorized
        int g = (blockIdx.x - 1024) * 256 + t;       // 0..524287
        int s = g >> 8;                              // 256 groups per row
        int cg = g & 255;
        int h = cg >> 4, w8 = cg & 15;
        size_t base = (size_t)s * QKV_N + DM + h * HD + w8 * 8;
        float4 cv = *(const float4*)&cosT[s * 64 + w8 * 4];
        float4 sv = *(const float4*)&sinT[s * 64 + w8 * 4];
        float cc[4] = {cv.x, cv.y, cv.z, cv.w};
        float ss[4] = {sv.x, sv.y, sv.z, sv.w};
        bf16x8 k = *(bf16x8*)&qkv[base];
        bf16x8 o;
#pragma unroll
        for (int p = 0; p < 4; ++p) {
            float re = (float)k[2 * p], im = (float)k[2 * p + 1];
            o[2 * p]     = (bf16)(re * cc[p] - im * ss[p]);
            o[2 * p + 1] = (bf16)(re * ss[p] + im * cc[p]);
        }
        *(bf16x8*)&qkv[base] = o;
        return;
    }
    // V transpose: vT[c][s] = qkv[s][2*DM + c], 64x64 tiles
    __shared__ bf16 tile[64][66];
    const int bx = (blockIdx.x & 31) * 64, by = (blockIdx.x >> 5) * 64;
#pragma unroll
    for (int j = 0; j < 4; ++j) {
        int idx = j * 256 + t;
        int r = idx >> 4, cg = idx & 15;             // r: seq-row, cg: channel/4
        *(bf16x4v*)&tile[r][cg * 4] =
            *(const bf16x4v*)&qkv[(size_t)(by + r) * QKV_N + 2 * DM + bx + cg * 4];
    }
    __syncthreads();
#pragma unroll
    for (int j = 0; j < 4; ++j) {
        int idx = j * 256 + t;
        int r = idx >> 4, cg = idx & 15;             // r: channel-row, cg: seq/4
        bf16x4v o;
        o.x = tile[cg * 4 + 0][r];
        o.y = tile[cg * 4 + 1][r];
        o.z = tile[cg * 4 + 2][r];
        o.w = tile[cg * 4 + 3][r];
        *(bf16x4v*)&vT[(size_t)(bx + r) * SEQ + by + cg * 4] = o;
    }
}

// ---- shared 128xBN GEMM body: C[.][N] = A[M][K] * Bt[N][K]^T --------------
template <typename OutT, int BN>
__device__ __forceinline__ void gemm_body(const bf16* __restrict__ A,
                                          const bf16* __restrict__ Bt,
                                          OutT* __restrict__ C,
                                          int N, int K, size_t bm, size_t bn,
                                          bf16* As, bf16* Bs) {
    constexpr int NI = BN / 32;
    const int t = threadIdx.x;
    const int lane = t & 63;
    const int w = t >> 6;
    const int wr = (w >> 1) * 64, wc = (w & 1) * (BN / 2);
    const int l15 = lane & 15, quad = lane >> 4;
    f32x4 acc[4][NI];
#pragma unroll
    for (int i = 0; i < 4; ++i)
#pragma unroll
        for (int j = 0; j < NI; ++j) acc[i][j] = (f32x4){0.f, 0.f, 0.f, 0.f};

    for (int kt = 0; kt < K; kt += 64) {
#pragma unroll
        for (int j = 0; j < 4; ++j) {
            int c = j * 256 + t;
            int row = c >> 3, g = ((c & 7) ^ (row & 7)) * 8;
            async16(&A[(bm + row) * K + kt + g], &As[c * 8]);
        }
#pragma unroll
        for (int j = 0; j < NI; ++j) {
            int c = j * 256 + t;
            int row = c >> 3, g = ((c & 7) ^ (row & 7)) * 8;
            async16(&Bt[(bn + row) * K + kt + g], &Bs[c * 8]);
        }
        __syncthreads();
#pragma unroll
        for (int kh = 0; kh < 2; ++kh) {
            bf16x8 af[4], bfm[NI];
#pragma unroll
            for (int mi = 0; mi < 4; ++mi)
                af[mi] = *(const bf16x8*)&As[sw_idx64(wr + mi * 16 + l15, kh * 4 + quad)];
#pragma unroll
            for (int ni = 0; ni < NI; ++ni)
                bfm[ni] = *(const bf16x8*)&Bs[sw_idx64(wc + ni * 16 + l15, kh * 4 + quad)];
#pragma unroll
            for (int mi = 0; mi < 4; ++mi)
#pragma unroll
                for (int ni = 0; ni < NI; ++ni)
                    acc[mi][ni] = __builtin_amdgcn_mfma_f32_16x16x32_bf16(
                        af[mi], bfm[ni], acc[mi][ni], 0, 0, 0);
        }
        __syncthreads();
    }
#pragma unroll
    for (int mi = 0; mi < 4; ++mi)
#pragma unroll
        for (int ni = 0; ni < NI; ++ni)
#pragma unroll
            for (int r = 0; r < 4; ++r) {
                size_t row = bm + wr + mi * 16 + quad * 4 + r;
                size_t col = bn + wc + ni * 16 + l15;
                C[row * (size_t)N + col] = (OutT)acc[mi][ni][r];
            }
}

template <typename OutT, int BN>
__global__ __launch_bounds__(256) void k_gemm_bt(const bf16* __restrict__ A,
                                                 const bf16* __restrict__ Bt,
                                                 OutT* __restrict__ C,
                                                 int M, int N, int K) {
    __shared__ bf16 As[128 * 64];
    __shared__ bf16 Bs[BN * 64];
    size_t bm = (size_t)blockIdx.y * 128, bn = (size_t)blockIdx.x * BN;
    gemm_body<OutT, BN>(A, Bt, C, N, K, bm, bn, As, Bs);
}

// ---- causal flash attention, HD=128, 64-key tiles, LDS double-buffer ------
// 256 threads = 4 waves; block owns 64 q-rows.  Balanced co-residency: blocks
// b and b+256 (same CU under round-robin XCD fill) share the head h and have
// qb summing to 31 -> every CU owns 33 tile-units (was 18..48).  Split waits:
// vmcnt(12) retires this tile's K before QK^T; vmcnt(8) retires V only when
// PV needs it -- the V stall hides under QK^T+softmax.  LDS 72KB -> 2/CU.
__global__ __launch_bounds__(256) void k_flash(const bf16* __restrict__ qkv,
                                               const bf16* __restrict__ vT,
                                               const float* __restrict__ cosT,
                                               const float* __restrict__ sinT,
                                               bf16* __restrict__ out) {
    __shared__ bf16 Ks[2][64 * 128];                 // [key][d] swizzled
    __shared__ bf16 Vs[2][128 * 64];                 // [ch][key] swizzled
    __shared__ bf16 Pl[4][16 * 64];                  // per-wave, swizzled
    const int t = threadIdx.x;
    const int lane = t & 63;
    const int w = t >> 6;
    const int l15 = lane & 15, quad = lane >> 4;
    const int b = blockIdx.x;
    const int h = (b & 7) * 2 + ((b >> 3) & 1);      // same h for b and b+256
    const int qb = (b < 256) ? (31 - (b >> 4)) : ((b >> 4) - 16);  // pair sums 31
    const int q0w = qb * 64 + w * 16;
    const float sc2 = 0.08838834764831845f * 1.4426950408889634f;  // /sqrt(128)*log2e

    const size_t qrow = (size_t)(q0w + l15) * QKV_N + h * HD;
    bf16x8 aq[4];
#pragma unroll
    for (int u = 0; u < 4; ++u)
        aq[u] = *(const bf16x8*)&qkv[qrow + u * 32 + quad * 8];
    // in-register Q RoPE: lane's 8 consecutive channels = 4 complete rot-pairs;
    // pair index i = u*16 + quad*4 + p, tables at cosT[(q0w+l15)*64 + i].
#pragma unroll
    for (int u = 0; u < 4; ++u) {
        float4 cv = *(const float4*)&cosT[(q0w + l15) * 64 + u * 16 + quad * 4];
        float4 sv = *(const float4*)&sinT[(q0w + l15) * 64 + u * 16 + quad * 4];
        float cc[4] = {cv.x, cv.y, cv.z, cv.w};
        float ss[4] = {sv.x, sv.y, sv.z, sv.w};
        bf16x8 q = aq[u], rq;
#pragma unroll
        for (int p = 0; p < 4; ++p) {
            float re = (float)q[2 * p], im = (float)q[2 * p + 1];
            rq[2 * p]     = (bf16)(re * cc[p] - im * ss[p]);
            rq[2 * p + 1] = (bf16)(re * ss[p] + im * cc[p]);
        }
        aq[u] = rq;
    }

    f32x4 o[8];
#pragma unroll
    for (int c = 0; c < 8; ++c) o[c] = (f32x4){0.f, 0.f, 0.f, 0.f};
    float l_r[4] = {0.f, 0.f, 0.f, 0.f};

    // staging descriptors: 1024 chunks per matrix per tile, 4/thread each
    int krow[4], kg[4], vrow[4], vg[4];
#pragma unroll
    for (int j = 0; j < 4; ++j) {
        int c = j * 256 + t;
        krow[j] = c >> 4; kg[j] = ((c & 15) ^ (krow[j] & 15)) * 8;   // 16 chunks/row
        vrow[j] = c >> 3; vg[j] = ((c & 7) ^ (vrow[j] & 7)) * 8;     //  8 chunks/row
    }
    // issue order matters for the split vmcnt counting: K first, then V.
    auto stage = [&](int buf, int kt2) {
        const int kb2 = kt2 * 64;
#pragma unroll
        for (int j = 0; j < 4; ++j)
            async16(&qkv[(size_t)(kb2 + krow[j]) * QKV_N + DM + h * HD + kg[j]],
                    &Ks[buf][(j * 256 + t) * 8]);
#pragma unroll
        for (int j = 0; j < 4; ++j)
            async16(&vT[(size_t)(h * HD + vrow[j]) * SEQ + kb2 + vg[j]],
                    &Vs[buf][(j * 256 + t) * 8]);
    };

    const int n64 = qb + 1;                          // exact causal tile count
    stage(0, 0);
    for (int kt = 0; kt < n64; ++kt) {
        const int cb = kt & 1;
        const int kbase = kt * 64;
        const bool pre = (kt + 1 < n64);
        if (pre) {
            stage(cb ^ 1, kt + 1);                   // prefetch next tile
            // retire THIS tile's K (4 loads); leave its V(4) + next tile's 8
            asm volatile("s_waitcnt vmcnt(12)" ::: "memory");
        } else {
            asm volatile("s_waitcnt vmcnt(4)" ::: "memory");   // K done, V pending
        }
        __builtin_amdgcn_s_barrier();                // all waves' K staged
        asm volatile("" ::: "memory");

        // ---- QK^T: 4 key sub-tiles x 4 d-chunks ----
        f32x4 s4[4];
        __builtin_amdgcn_s_setprio(1);
#pragma unroll
        for (int sub = 0; sub < 4; ++sub) {
            f32x4 z = (f32x4){0.f, 0.f, 0.f, 0.f};
#pragma unroll
            for (int u = 0; u < 4; ++u) {
                bf16x8 kv = *(const bf16x8*)&Ks[cb][sw_idx128(sub * 16 + l15, u * 4 + quad)];
                z = __builtin_amdgcn_mfma_f32_16x16x32_bf16(aq[u], kv, z, 0, 0, 0);
            }
            s4[sub] = z;
        }
        __builtin_amdgcn_s_setprio(0);
        const bool masked = (kt == n64 - 1);
#pragma unroll
        for (int sub = 0; sub < 4; ++sub)
#pragma unroll
            for (int r = 0; r < 4; ++r) {
                float p = __builtin_amdgcn_exp2f(s4[sub][r] * sc2);
                if (masked)
                    p = (kbase + sub * 16 + l15 <= q0w + quad * 4 + r) ? p : 0.f;
                l_r[r] += p;
                int rowp = quad * 4 + r;
                int col = sub * 16 + l15;
                Pl[w][(rowp * 8 + ((col >> 3) ^ (rowp & 7))) * 8 + (col & 7)] = (bf16)p;
            }
        // V stall hidden under QK^T+softmax: retire this tile's V, all waves
        if (pre) asm volatile("s_waitcnt vmcnt(8)" ::: "memory");
        else     asm volatile("s_waitcnt vmcnt(0)" ::: "memory");
        __builtin_amdgcn_s_barrier();                // all waves' V staged
        __asm__ __volatile__("s_waitcnt lgkmcnt(0)" ::: "memory");  // own P visible
        bf16x8 pf[2];
#pragma unroll
        for (int kk = 0; kk < 2; ++kk)
            pf[kk] = *(const bf16x8*)&Pl[w][sw_idx64(l15, kk * 4 + quad)];
        __builtin_amdgcn_s_setprio(1);
#pragma unroll
        for (int c = 0; c < 8; ++c)
#pragma unroll
            for (int kk = 0; kk < 2; ++kk) {
                bf16x8 vb = *(const bf16x8*)&Vs[cb][sw_idx64(c * 16 + l15, kk * 4 + quad)];
                o[c] = __builtin_amdgcn_mfma_f32_16x16x32_bf16(pf[kk], vb, o[c], 0, 0, 0);
            }
        __builtin_amdgcn_s_setprio(0);
        asm volatile("" ::: "memory");
        __builtin_amdgcn_s_barrier();                // all waves done reading buf cb
        asm volatile("" ::: "memory");
    }

    float rl[4];
#pragma unroll
    for (int r = 0; r < 4; ++r) {
        float l = l_r[r];
        l += __shfl_xor(l, 1, 16);
        l += __shfl_xor(l, 2, 16);
        l += __shfl_xor(l, 4, 16);
        l += __shfl_xor(l, 8, 16);
        rl[r] = 1.0f / l;
    }
#pragma unroll
    for (int c = 0; c < 8; ++c)
#pragma unroll
        for (int r = 0; r < 4; ++r)
            out[(size_t)(q0w + quad * 4 + r) * DM + h * HD + c * 16 + l15] =
                (bf16)(o[c][r] * rl[r]);
}

extern "C" void kernel_launch(void* const* d_in, const int* in_sizes, int n_in,
                              void* d_out, int out_size, void* d_ws, size_t ws_size,
                              hipStream_t stream) {
    const float* x  = (const float*)d_in[0];
    const float* fc = (const float*)d_in[1];
    const float* fs = (const float*)d_in[2];
    // d_in[3] = mask (unused; causal mask applied analytically)
    const float* wq = (const float*)d_in[4];
    const float* wk = (const float*)d_in[5];
    const float* wv = (const float*)d_in[6];
    const float* wo = (const float*)d_in[7];
    float* out = (float*)d_out;

    char* ws = (char*)d_ws;
    bf16* xb  = (bf16*)(ws);                          //  8MB, reused as attn_out
    bf16* wT  = (bf16*)(ws + (size_t)(8u  << 20));    // 24MB  (wq^T|wk^T|wv^T)
    bf16* woT = (bf16*)(ws + (size_t)(32u << 20));    //  8MB
    bf16* qkv = (bf16*)(ws + (size_t)(40u << 20));    // 24MB  [seq][6144]
    bf16* vT  = (bf16*)(ws + (size_t)(64u << 20));    //  8MB  [c][seq]

    k_prep<<<dim3(32, 32, 5), 256, 0, stream>>>(wq, wk, wv, wo, wT, woT, x, xb);
    k_gemm_bt<bf16, 128><<<dim3(48, 16), 256, 0, stream>>>(xb, wT, qkv, SEQ, QKV_N, DM);
    k_rope_vt<<<3072, 256, 0, stream>>>(qkv, fc, fs, vT);
    k_flash<<<512, 256, 0, stream>>>(qkv, vT, fc, fs, xb);
    k_gemm_bt<float, 64><<<dim3(32, 16), 256, 0, stream>>>(xb, woT, out, SEQ, DM, DM);
}